// Round 8
// baseline (718.464 us; speedup 1.0000x reference)
//
#include <hip/hip_runtime.h>
#include <math.h>

#define D_FEAT 128
#define SCAN_ITEMS 2048   // items per scan block (256 thr * 8)
#define REP 4             // DIAGNOSTIC: reduce work repeated REP times (idempotent).
                          // Set to 1 next round once per-kernel cost is attributed.

typedef float f32x4 __attribute__((ext_vector_type(4)));
typedef short short8 __attribute__((ext_vector_type(8)));

// float -> bf16 (RNE), on raw bits
__device__ __forceinline__ unsigned short f2bf(float f) {
    unsigned int u = __float_as_uint(f);
    u += 0x7FFFu + ((u >> 16) & 1u);
    return (unsigned short)(u >> 16);
}

// setup: zero histogram counters + build fragment-major bf16 W:
// Wfrag[((c*8+s)*64+l)*8+i] = bf16( W[col=c*16+(l&15)][k=s*32+((l>>4)<<3)+i] )
// so a B-fragment for col-tile c, k-step s is a coalesced 16B/lane load.
__global__ __launch_bounds__(256) void setup_kernel(const float* __restrict__ W,
                                                    unsigned short* __restrict__ Wfrag,
                                                    int* __restrict__ cnt, int M) {
    int i = blockIdx.x * 256 + threadIdx.x;
    if (i < 2 * D_FEAT * D_FEAT) {
        int ii = i & 7, lf = (i >> 3) & 63, sf = (i >> 9) & 7, cf = i >> 12;
        int col = cf * 16 + (lf & 15);
        int k   = sf * 32 + ((lf >> 4) << 3) + ii;
        Wfrag[i] = f2bf(W[(size_t)col * (2 * D_FEAT) + k]);
    }
    if (i < M) cnt[i] = 0;
}

// 1) histogram of segment ids (int4 loads)
__global__ __launch_bounds__(256) void hist_kernel(const int* __restrict__ index,
                                                   int* __restrict__ cnt, int n4, int n) {
    int i = blockIdx.x * 256 + threadIdx.x;
    if (i < n4) {
        int4 v = reinterpret_cast<const int4*>(index)[i];
        atomicAdd(&cnt[v.x], 1);
        atomicAdd(&cnt[v.y], 1);
        atomicAdd(&cnt[v.z], 1);
        atomicAdd(&cnt[v.w], 1);
    }
    int rem = 4 * n4 + i;
    if (i < n - 4 * n4) atomicAdd(&cnt[index[rem]], 1);
}

// 2a) per-block sums of cnt (coalesced)
__global__ __launch_bounds__(256) void blocksum_kernel(const int* __restrict__ cnt,
                                                       int* __restrict__ bsum, int n) {
    __shared__ int sh[256];
    const int b = blockIdx.x, t = threadIdx.x;
    const int base = b * SCAN_ITEMS;
    int s = 0;
    #pragma unroll
    for (int j = 0; j < 8; ++j) {
        int i = base + j * 256 + t;
        if (i < n) s += cnt[i];
    }
    sh[t] = s;
    __syncthreads();
    for (int st = 128; st > 0; st >>= 1) {
        if (t < st) sh[t] += sh[t + st];
        __syncthreads();
    }
    if (t == 0) bsum[b] = sh[0];
}

// 2b) single-wave scan of block sums (nblk <= 64); also writes off[n] = total
__global__ __launch_bounds__(64) void scanblk_kernel(const int* __restrict__ bsum,
                                                     int* __restrict__ boff,
                                                     int* __restrict__ off,
                                                     int n, int nblk) {
    int t = threadIdx.x;
    int v = (t < nblk) ? bsum[t] : 0;
    int orig = v;
    #pragma unroll
    for (int d = 1; d < 64; d <<= 1) {
        int u = __shfl_up(v, d);
        if (t >= d) v += u;
    }
    if (t < nblk) boff[t] = v - orig;   // exclusive
    if (t == 63) off[n] = v;            // grand total
}

// 2c) apply: per-block exclusive scan over its 2048 items -> off, cursor
__global__ __launch_bounds__(256) void apply_kernel(const int* __restrict__ cnt,
                                                    const int* __restrict__ boff,
                                                    int* __restrict__ off,
                                                    int* __restrict__ cursor, int n) {
    __shared__ int sh[SCAN_ITEMS];
    __shared__ int ts[256];
    const int b = blockIdx.x, t = threadIdx.x;
    const int base = b * SCAN_ITEMS;
    #pragma unroll
    for (int j = 0; j < 8; ++j) {
        int i = base + j * 256 + t;
        sh[j * 256 + t] = (i < n) ? cnt[i] : 0;
    }
    __syncthreads();
    int s = 0;
    #pragma unroll
    for (int j = 0; j < 8; ++j) s += sh[t * 8 + j];
    ts[t] = s;
    __syncthreads();
    for (int st = 1; st < 256; st <<= 1) {
        int u = (t >= st) ? ts[t - st] : 0;
        __syncthreads();
        ts[t] += u;
        __syncthreads();
    }
    int run = boff[b] + ts[t] - s;
    #pragma unroll
    for (int j = 0; j < 8; ++j) {
        int i = base + t * 8 + j;
        if (i < n) {
            off[i] = run;
            cursor[i] = run;
            run += sh[t * 8 + j];
        }
    }
}

// 3) scatter edge ids into segment-sorted order (int4 loads)
__global__ __launch_bounds__(256) void order_kernel(const int* __restrict__ index,
                                                    int* __restrict__ cursor,
                                                    int* __restrict__ order, int n4, int n) {
    int i = blockIdx.x * 256 + threadIdx.x;
    if (i < n4) {
        int4 v = reinterpret_cast<const int4*>(index)[i];
        int e = 4 * i;
        order[atomicAdd(&cursor[v.x], 1)] = e;
        order[atomicAdd(&cursor[v.y], 1)] = e + 1;
        order[atomicAdd(&cursor[v.z], 1)] = e + 2;
        order[atomicAdd(&cursor[v.w], 1)] = e + 3;
    }
    int rem = 4 * n4 + i;
    if (i < n - 4 * n4) order[atomicAdd(&cursor[index[rem]], 1)] = rem;
}

// 4) one wave per segment, wave-uniform broadcast-gather; output row in bf16:
//    A_b[wid][0:128] = bf16(sum), A_b[wid][128:256] = bf16(max).
//    DIAGNOSTIC: whole body repeated REP times (idempotent); memory clobber
//    between reps prevents the compiler from eliding earlier reps.
__global__ __launch_bounds__(256) void reduce_kernel(
    const float* __restrict__ src, const int* __restrict__ order,
    const int* __restrict__ off, unsigned short* __restrict__ A_b, int nseg)
{
    int wid  = (blockIdx.x * 256 + threadIdx.x) >> 6;
    int lane = threadIdx.x & 63;
    if (wid >= nseg) return;

    const int start = off[wid], end = off[wid + 1];
    const int fo = lane * 2;   // feature pair 2l, 2l+1

    for (int rep = 0; rep < REP; ++rep) {
        float2 s0 = make_float2(0.f, 0.f), s1 = make_float2(0.f, 0.f);
        float2 m0 = make_float2(-INFINITY, -INFINITY), m1 = m0;

        for (int base = start; base < end; base += 64) {
            int idx = base + lane;
            int eo  = (idx < end) ? order[idx] : 0;
            int lim = end - base; if (lim > 64) lim = 64;
            int j = 0;
            #pragma unroll 2
            for (; j + 1 < lim; j += 2) {
                int e0 = __shfl(eo, j);
                int e1 = __shfl(eo, j + 1);
                float2 v0 = *reinterpret_cast<const float2*>(src + (size_t)e0 * D_FEAT + fo);
                float2 v1 = *reinterpret_cast<const float2*>(src + (size_t)e1 * D_FEAT + fo);
                s0.x += v0.x; s0.y += v0.y;
                s1.x += v1.x; s1.y += v1.y;
                m0.x = fmaxf(m0.x, v0.x); m0.y = fmaxf(m0.y, v0.y);
                m1.x = fmaxf(m1.x, v1.x); m1.y = fmaxf(m1.y, v1.y);
            }
            if (j < lim) {
                int e0 = __shfl(eo, j);
                float2 v0 = *reinterpret_cast<const float2*>(src + (size_t)e0 * D_FEAT + fo);
                s0.x += v0.x; s0.y += v0.y;
                m0.x = fmaxf(m0.x, v0.x); m0.y = fmaxf(m0.y, v0.y);
            }
        }

        float2 sum = make_float2(s0.x + s1.x, s0.y + s1.y);
        float2 mx  = make_float2(fmaxf(m0.x, m1.x), fmaxf(m0.y, m1.y));
        if (end == start) { mx.x = 0.f; mx.y = 0.f; }

        unsigned int sp = (unsigned int)f2bf(sum.x) | ((unsigned int)f2bf(sum.y) << 16);
        unsigned int mp = (unsigned int)f2bf(mx.x)  | ((unsigned int)f2bf(mx.y)  << 16);
        unsigned short* row = A_b + (size_t)wid * (2 * D_FEAT);
        *reinterpret_cast<unsigned int*>(row + fo)          = sp;
        *reinterpret_cast<unsigned int*>(row + D_FEAT + fo) = mp;

        asm volatile("" ::: "memory");   // keep every rep live (rule #17)
    }
}

// 5) MFMA GEMM: out[M,128] = A_b[M,256](bf16) @ W^T + bias, fp32 accum.
//    Block = 64 rows x 128 cols, 4 waves; wave w -> rows [m0+16w, +16).
//    A-frag: row = l&15, k = s*32 + (l>>4)*8 + i (16B/lane from row-major A_b).
//    B-frag: coalesced 16B/lane from fragment-major Wfrag.
//    D: col = l&15 (+16c), row = (l>>4)*4 + r  [HW-verified mapping].
__global__ __launch_bounds__(256) void gemm_mfma_kernel(
    const unsigned short* __restrict__ A_b, const unsigned short* __restrict__ Wfrag,
    const float* __restrict__ bias, float* __restrict__ out, int M)
{
    const int w  = threadIdx.x >> 6;
    const int l  = threadIdx.x & 63;
    const int m0 = blockIdx.x * 64 + w * 16;
    if (m0 >= M) return;   // whole-wave tail (rows padded in A_b allocation)

    const int arow = m0 + (l & 15);
    const int kgrp = (l >> 4) << 3;

    f32x4 acc[8];
    #pragma unroll
    for (int c = 0; c < 8; ++c) acc[c] = (f32x4){0.f, 0.f, 0.f, 0.f};

    #pragma unroll
    for (int s = 0; s < 8; ++s) {
        short8 a = *reinterpret_cast<const short8*>(A_b + (size_t)arow * 256 + s * 32 + kgrp);
        #pragma unroll
        for (int c = 0; c < 8; ++c) {
            short8 b = *reinterpret_cast<const short8*>(Wfrag + (((size_t)(c * 8 + s)) * 64 + l) * 8);
            acc[c] = __builtin_amdgcn_mfma_f32_16x16x32_bf16(a, b, acc[c], 0, 0, 0);
        }
    }

    const int r0   = m0 + ((l >> 4) << 2);
    const int colb = l & 15;
    #pragma unroll
    for (int c = 0; c < 8; ++c) {
        int col = c * 16 + colb;
        float bv = bias[col];
        #pragma unroll
        for (int r = 0; r < 4; ++r) {
            int rw = r0 + r;
            if (rw < M) out[(size_t)rw * D_FEAT + col] = acc[c][r] + bv;
        }
    }
}

extern "C" void kernel_launch(void* const* d_in, const int* in_sizes, int n_in,
                              void* d_out, int out_size, void* d_ws, size_t ws_size,
                              hipStream_t stream) {
    const float* src   = (const float*)d_in[0];
    const int*   index = (const int*)d_in[1];
    const float* W     = (const float*)d_in[2];
    const float* bias  = (const float*)d_in[3];

    const int n_edges = in_sizes[1];            // 1,600,000
    const int M       = out_size / D_FEAT;      // 50,000
    const int Mpad    = (M + 63) & ~63;         // pad rows so tail waves read in-bounds

    // workspace layout (16B-aligned chunks)
    unsigned short* A_b   = (unsigned short*)d_ws;            // Mpad * 256 bf16
    unsigned short* Wfrag = A_b + (size_t)Mpad * 2 * D_FEAT;  // 32768 bf16 (64KB)
    int*   cnt    = (int*)(Wfrag + 2 * D_FEAT * D_FEAT);      // M
    int*   off    = cnt + M;                                  // M + 1
    int*   cursor = off + M + 1;                              // M
    int*   order  = cursor + M;                               // n_edges
    int*   bsum   = order + n_edges;                          // <= 64
    int*   boff   = bsum + 64;                                // <= 64

    const int nblk = (M + SCAN_ITEMS - 1) / SCAN_ITEMS;       // 25

    setup_kernel<<<(max(M, 2 * D_FEAT * D_FEAT) + 255) / 256, 256, 0, stream>>>(W, Wfrag, cnt, M);

    int n4 = n_edges / 4;
    int eb4 = (max(n4, n_edges - 4 * n4) + 255) / 256;
    hist_kernel<<<eb4, 256, 0, stream>>>(index, cnt, n4, n_edges);

    blocksum_kernel<<<nblk, 256, 0, stream>>>(cnt, bsum, M);
    scanblk_kernel<<<1, 64, 0, stream>>>(bsum, boff, off, M, nblk);
    apply_kernel<<<nblk, 256, 0, stream>>>(cnt, boff, off, cursor, M);

    order_kernel<<<eb4, 256, 0, stream>>>(index, cursor, order, n4, n_edges);

    int rb = (M * 64 + 255) / 256;
    reduce_kernel<<<rb, 256, 0, stream>>>(src, order, off, A_b, M);

    gemm_mfma_kernel<<<(M + 63) / 64, 256, 0, stream>>>(A_b, Wfrag, bias, (float*)d_out, M);
}

// Round 9
// 404.943 us; speedup vs baseline: 1.7742x; 1.7742x over previous
//
#include <hip/hip_runtime.h>
#include <math.h>

#define D_FEAT 128
#define SCAN_ITEMS 2048   // items per scan block (256 thr * 8)

typedef float f32x4 __attribute__((ext_vector_type(4)));
typedef short short8 __attribute__((ext_vector_type(8)));

// float -> bf16 (RNE), on raw bits
__device__ __forceinline__ unsigned short f2bf(float f) {
    unsigned int u = __float_as_uint(f);
    u += 0x7FFFu + ((u >> 16) & 1u);
    return (unsigned short)(u >> 16);
}

// setup: zero histogram counters + build fragment-major bf16 W:
// Wfrag[((c*8+s)*64+l)*8+i] = bf16( W[col=c*16+(l&15)][k=s*32+((l>>4)<<3)+i] )
__global__ __launch_bounds__(256) void setup_kernel(const float* __restrict__ W,
                                                    unsigned short* __restrict__ Wfrag,
                                                    int* __restrict__ cnt, int M) {
    int i = blockIdx.x * 256 + threadIdx.x;
    if (i < 2 * D_FEAT * D_FEAT) {
        int ii = i & 7, lf = (i >> 3) & 63, sf = (i >> 9) & 7, cf = i >> 12;
        int col = cf * 16 + (lf & 15);
        int k   = sf * 32 + ((lf >> 4) << 3) + ii;
        Wfrag[i] = f2bf(W[(size_t)col * (2 * D_FEAT) + k]);
    }
    if (i < M) cnt[i] = 0;
}

// 1) histogram of segment ids (int4 loads)
__global__ __launch_bounds__(256) void hist_kernel(const int* __restrict__ index,
                                                   int* __restrict__ cnt, int n4, int n) {
    int i = blockIdx.x * 256 + threadIdx.x;
    if (i < n4) {
        int4 v = reinterpret_cast<const int4*>(index)[i];
        atomicAdd(&cnt[v.x], 1);
        atomicAdd(&cnt[v.y], 1);
        atomicAdd(&cnt[v.z], 1);
        atomicAdd(&cnt[v.w], 1);
    }
    int rem = 4 * n4 + i;
    if (i < n - 4 * n4) atomicAdd(&cnt[index[rem]], 1);
}

// 2a) per-block sums of cnt (coalesced)
__global__ __launch_bounds__(256) void blocksum_kernel(const int* __restrict__ cnt,
                                                       int* __restrict__ bsum, int n) {
    __shared__ int sh[256];
    const int b = blockIdx.x, t = threadIdx.x;
    const int base = b * SCAN_ITEMS;
    int s = 0;
    #pragma unroll
    for (int j = 0; j < 8; ++j) {
        int i = base + j * 256 + t;
        if (i < n) s += cnt[i];
    }
    sh[t] = s;
    __syncthreads();
    for (int st = 128; st > 0; st >>= 1) {
        if (t < st) sh[t] += sh[t + st];
        __syncthreads();
    }
    if (t == 0) bsum[b] = sh[0];
}

// 2b) single-wave scan of block sums (nblk <= 64); also writes off[n] = total
__global__ __launch_bounds__(64) void scanblk_kernel(const int* __restrict__ bsum,
                                                     int* __restrict__ boff,
                                                     int* __restrict__ off,
                                                     int n, int nblk) {
    int t = threadIdx.x;
    int v = (t < nblk) ? bsum[t] : 0;
    int orig = v;
    #pragma unroll
    for (int d = 1; d < 64; d <<= 1) {
        int u = __shfl_up(v, d);
        if (t >= d) v += u;
    }
    if (t < nblk) boff[t] = v - orig;   // exclusive
    if (t == 63) off[n] = v;            // grand total
}

// 2c) apply: per-block exclusive scan over its 2048 items -> off, cursor
__global__ __launch_bounds__(256) void apply_kernel(const int* __restrict__ cnt,
                                                    const int* __restrict__ boff,
                                                    int* __restrict__ off,
                                                    int* __restrict__ cursor, int n) {
    __shared__ int sh[SCAN_ITEMS];
    __shared__ int ts[256];
    const int b = blockIdx.x, t = threadIdx.x;
    const int base = b * SCAN_ITEMS;
    #pragma unroll
    for (int j = 0; j < 8; ++j) {
        int i = base + j * 256 + t;
        sh[j * 256 + t] = (i < n) ? cnt[i] : 0;
    }
    __syncthreads();
    int s = 0;
    #pragma unroll
    for (int j = 0; j < 8; ++j) s += sh[t * 8 + j];
    ts[t] = s;
    __syncthreads();
    for (int st = 1; st < 256; st <<= 1) {
        int u = (t >= st) ? ts[t - st] : 0;
        __syncthreads();
        ts[t] += u;
        __syncthreads();
    }
    int run = boff[b] + ts[t] - s;
    #pragma unroll
    for (int j = 0; j < 8; ++j) {
        int i = base + t * 8 + j;
        if (i < n) {
            off[i] = run;
            cursor[i] = run;
            run += sh[t * 8 + j];
        }
    }
}

// 3) scatter edge ids into segment-sorted order (int4 loads)
__global__ __launch_bounds__(256) void order_kernel(const int* __restrict__ index,
                                                    int* __restrict__ cursor,
                                                    int* __restrict__ order, int n4, int n) {
    int i = blockIdx.x * 256 + threadIdx.x;
    if (i < n4) {
        int4 v = reinterpret_cast<const int4*>(index)[i];
        int e = 4 * i;
        order[atomicAdd(&cursor[v.x], 1)] = e;
        order[atomicAdd(&cursor[v.y], 1)] = e + 1;
        order[atomicAdd(&cursor[v.z], 1)] = e + 2;
        order[atomicAdd(&cursor[v.w], 1)] = e + 3;
    }
    int rem = 4 * n4 + i;
    if (i < n - 4 * n4) order[atomicAdd(&cursor[index[rem]], 1)] = rem;
}

// 4) one wave per segment. Coalesced 64-wide order-chunk load, then a
//    UNIFORM-trip-count loop: half-wave h (32 lanes, float4 = 16B/lane)
//    gathers row __shfl(eo, j+h); out-of-range jj predicated off.
//    Halves combined via shfl_xor(32); half0 stores sum, half1 stores max.
__global__ __launch_bounds__(256) void reduce_kernel(
    const float* __restrict__ src, const int* __restrict__ order,
    const int* __restrict__ off, unsigned short* __restrict__ A_b, int nseg)
{
    int wid  = (blockIdx.x * 256 + threadIdx.x) >> 6;
    int lane = threadIdx.x & 63;
    if (wid >= nseg) return;
    const int half = lane >> 5;
    const int fl   = (lane & 31) << 2;   // feature offset 0..124

    const int start = off[wid], end = off[wid + 1];

    f32x4 s = {0.f, 0.f, 0.f, 0.f};
    f32x4 m = {-INFINITY, -INFINITY, -INFINITY, -INFINITY};

    for (int base = start; base < end; base += 64) {
        int idx = base + lane;
        int eo  = (idx < end) ? order[idx] : 0;      // coalesced 256B wave load
        int lim = end - base; if (lim > 64) lim = 64;
        #pragma unroll 2
        for (int j = 0; j < lim; j += 2) {           // uniform trip count
            int jj = j + half;
            int e  = __shfl(eo, jj);                 // all 64 lanes active
            if (jj < lim) {                          // predicate half-wave tail
                f32x4 v = *reinterpret_cast<const f32x4*>(src + (size_t)e * D_FEAT + fl);
                s.x += v.x; s.y += v.y; s.z += v.z; s.w += v.w;
                m.x = fmaxf(m.x, v.x); m.y = fmaxf(m.y, v.y);
                m.z = fmaxf(m.z, v.z); m.w = fmaxf(m.w, v.w);
            }
        }
    }

    // combine the two halves
    s.x += __shfl_xor(s.x, 32); s.y += __shfl_xor(s.y, 32);
    s.z += __shfl_xor(s.z, 32); s.w += __shfl_xor(s.w, 32);
    m.x = fmaxf(m.x, __shfl_xor(m.x, 32)); m.y = fmaxf(m.y, __shfl_xor(m.y, 32));
    m.z = fmaxf(m.z, __shfl_xor(m.z, 32)); m.w = fmaxf(m.w, __shfl_xor(m.w, 32));

    if (end == start) { m.x = 0.f; m.y = 0.f; m.z = 0.f; m.w = 0.f; }  // empty -> 0

    // pack 4 bf16 (8B per lane); half0 -> sum row, half1 -> max row
    const f32x4 o = (half == 0) ? s : m;
    unsigned int lo = (unsigned int)f2bf(o.x) | ((unsigned int)f2bf(o.y) << 16);
    unsigned int hi = (unsigned int)f2bf(o.z) | ((unsigned int)f2bf(o.w) << 16);
    unsigned short* row = A_b + (size_t)wid * (2 * D_FEAT) + half * D_FEAT;
    uint2 pk = make_uint2(lo, hi);
    *reinterpret_cast<uint2*>(row + fl) = pk;
}

// 5) MFMA GEMM: out[M,128] = A_b[M,256](bf16) @ W^T + bias, fp32 accum.
__global__ __launch_bounds__(256) void gemm_mfma_kernel(
    const unsigned short* __restrict__ A_b, const unsigned short* __restrict__ Wfrag,
    const float* __restrict__ bias, float* __restrict__ out, int M)
{
    const int w  = threadIdx.x >> 6;
    const int l  = threadIdx.x & 63;
    const int m0 = blockIdx.x * 64 + w * 16;
    if (m0 >= M) return;

    const int arow = m0 + (l & 15);
    const int kgrp = (l >> 4) << 3;

    f32x4 acc[8];
    #pragma unroll
    for (int c = 0; c < 8; ++c) acc[c] = (f32x4){0.f, 0.f, 0.f, 0.f};

    #pragma unroll
    for (int s = 0; s < 8; ++s) {
        short8 a = *reinterpret_cast<const short8*>(A_b + (size_t)arow * 256 + s * 32 + kgrp);
        #pragma unroll
        for (int c = 0; c < 8; ++c) {
            short8 b = *reinterpret_cast<const short8*>(Wfrag + (((size_t)(c * 8 + s)) * 64 + l) * 8);
            acc[c] = __builtin_amdgcn_mfma_f32_16x16x32_bf16(a, b, acc[c], 0, 0, 0);
        }
    }

    const int r0   = m0 + ((l >> 4) << 2);
    const int colb = l & 15;
    #pragma unroll
    for (int c = 0; c < 8; ++c) {
        int col = c * 16 + colb;
        float bv = bias[col];
        #pragma unroll
        for (int r = 0; r < 4; ++r) {
            int rw = r0 + r;
            if (rw < M) out[(size_t)rw * D_FEAT + col] = acc[c][r] + bv;
        }
    }
}

extern "C" void kernel_launch(void* const* d_in, const int* in_sizes, int n_in,
                              void* d_out, int out_size, void* d_ws, size_t ws_size,
                              hipStream_t stream) {
    const float* src   = (const float*)d_in[0];
    const int*   index = (const int*)d_in[1];
    const float* W     = (const float*)d_in[2];
    const float* bias  = (const float*)d_in[3];

    const int n_edges = in_sizes[1];            // 1,600,000
    const int M       = out_size / D_FEAT;      // 50,000
    const int Mpad    = (M + 63) & ~63;

    // workspace layout
    unsigned short* A_b   = (unsigned short*)d_ws;            // Mpad * 256 bf16
    unsigned short* Wfrag = A_b + (size_t)Mpad * 2 * D_FEAT;  // 32768 bf16
    int*   cnt    = (int*)(Wfrag + 2 * D_FEAT * D_FEAT);      // M
    int*   off    = cnt + M;                                  // M + 1
    int*   cursor = off + M + 1;                              // M
    int*   order  = cursor + M;                               // n_edges
    int*   bsum   = order + n_edges;                          // <= 64
    int*   boff   = bsum + 64;                                // <= 64

    const int nblk = (M + SCAN_ITEMS - 1) / SCAN_ITEMS;       // 25

    setup_kernel<<<(max(M, 2 * D_FEAT * D_FEAT) + 255) / 256, 256, 0, stream>>>(W, Wfrag, cnt, M);

    int n4 = n_edges / 4;
    int eb4 = (max(n4, n_edges - 4 * n4) + 255) / 256;
    hist_kernel<<<eb4, 256, 0, stream>>>(index, cnt, n4, n_edges);

    blocksum_kernel<<<nblk, 256, 0, stream>>>(cnt, bsum, M);
    scanblk_kernel<<<1, 64, 0, stream>>>(bsum, boff, off, M, nblk);
    apply_kernel<<<nblk, 256, 0, stream>>>(cnt, boff, off, cursor, M);

    order_kernel<<<eb4, 256, 0, stream>>>(index, cursor, order, n4, n_edges);

    int rb = (M * 64 + 255) / 256;
    reduce_kernel<<<rb, 256, 0, stream>>>(src, order, off, A_b, M);

    gemm_mfma_kernel<<<(M + 63) / 64, 256, 0, stream>>>(A_b, Wfrag, bias, (float*)d_out, M);
}